// Round 8
// baseline (187.637 us; speedup 1.0000x reference)
//
#include <hip/hip_runtime.h>

#define SQL  1024
#define EDIM 256
#define NHD  8
#define NKV  (NHD * 3 * EDIM)   // 6144
#define MROWS (4 * SQL)         // 4096

typedef short bf16x8 __attribute__((ext_vector_type(8)));
typedef short bf16x4 __attribute__((ext_vector_type(4)));
typedef float f32x4 __attribute__((ext_vector_type(4)));

// ---- 16x16x16 bf16 MFMA builtin resolution (guarded; fallback = zero-padded 16x16x32)
#if defined(__has_builtin)
#if __has_builtin(__builtin_amdgcn_mfma_f32_16x16x16bf16_1k)
#define MFMA16(a, b, c) __builtin_amdgcn_mfma_f32_16x16x16bf16_1k(a, b, c, 0, 0, 0)
#define HAVE_MFMA16 1
#elif __has_builtin(__builtin_amdgcn_mfma_f32_16x16x16_bf16)
#define MFMA16(a, b, c) __builtin_amdgcn_mfma_f32_16x16x16_bf16(a, b, c, 0, 0, 0)
#define HAVE_MFMA16 1
#else
#define HAVE_MFMA16 0
#endif
#else
#define HAVE_MFMA16 0
#endif

// Ps row stride (shorts): 20 (=40B, b64-aligned) for the 16x16x16 path;
// 24 (=48B, 16B-aligned) for the b128 fallback path.
constexpr int PSTR = HAVE_MFMA16 ? 20 : 24;

__device__ __forceinline__ unsigned short f2bf(float f) {
  unsigned u = __float_as_uint(f);
  u += 0x7fff + ((u >> 16) & 1);   // round-to-nearest-even (finite values)
  return (unsigned short)(u >> 16);
}

// async 16B global->LDS (direct-to-shared DMA; LDS dest must be
// wave-uniform base + lane*16 — all call sites use flat tid*16B forms)
__device__ __forceinline__ void g2lds16(const void* g, void* l) {
  __builtin_amdgcn_global_load_lds(
      (const __attribute__((address_space(1))) unsigned int*)g,
      (__attribute__((address_space(3))) unsigned int*)l, 16, 0, 0);
}

__device__ __forceinline__ void storev(float* p, float v) { *p = v; }
__device__ __forceinline__ void storev(unsigned short* p, float v) { *p = f2bf(v); }

// =====================================================================
// fused fp32 -> bf16 cast for all three inputs, 8 elems/thread.
// =====================================================================
__global__ __launch_bounds__(256) void cast3_bf16(
    const float* __restrict__ s0, unsigned short* __restrict__ d0, int n0,
    const float* __restrict__ s1, unsigned short* __restrict__ d1, int n1,
    const float* __restrict__ s2, unsigned short* __restrict__ d2, int n2) {
  int i = blockIdx.x * 256 + threadIdx.x;
  const float* s; unsigned short* d;
  if (i < n0) { s = s0; d = d0; }
  else if (i < n0 + n1) { i -= n0; s = s1; d = d1; }
  else { i -= n0 + n1; if (i >= n2) return; s = s2; d = d2; }
  float4 a = ((const float4*)s)[2 * i];
  float4 b = ((const float4*)s)[2 * i + 1];
  union { unsigned short u[8]; ulonglong2 v; } t;
  t.u[0] = f2bf(a.x); t.u[1] = f2bf(a.y); t.u[2] = f2bf(a.z); t.u[3] = f2bf(a.w);
  t.u[4] = f2bf(b.x); t.u[5] = f2bf(b.y); t.u[6] = f2bf(b.z); t.u[7] = f2bf(b.w);
  ((ulonglong2*)d)[i] = t.v;
}

// =====================================================================
// bf16 MFMA NT-GEMM, double-buffered global_load_lds staging.
// (round-0 proven version)
// =====================================================================
template <int BM, int BN, typename OutT>
__global__ __launch_bounds__(256) void gemm_mfma(
    const unsigned short* __restrict__ A, const unsigned short* __restrict__ B,
    const float* __restrict__ bias, OutT* __restrict__ C,
    int M, int N, int K) {
  constexpr int TM = BM / 32, TN = BN / 32;
  __shared__ __align__(16) unsigned short As[2][BM * 32];
  __shared__ __align__(16) unsigned short Bs[2][BN * 32];
  const int tid = threadIdx.x;
  const int wave = tid >> 6, lane = tid & 63;
  const int quad = lane >> 4, l16 = lane & 15;
  const int wm = (wave >> 1) * (BM / 2), wn = (wave & 1) * (BN / 2);
  const int m0 = blockIdx.x * BM, n0 = blockIdx.y * BN;
  const int sw = (l16 >> 1) & 3;

  f32x4 acc[TM][TN];
  #pragma unroll
  for (int i = 0; i < TM; i++)
    #pragma unroll
    for (int j = 0; j < TN; j++) acc[i][j] = {0.f, 0.f, 0.f, 0.f};

  auto stage = [&](int k0, int bb) {
    #pragma unroll
    for (int it = 0; it < BM / 64; it++) {
      int flat = it * 256 + tid;
      int row = flat >> 2;
      int cg = (flat & 3) ^ ((row >> 1) & 3);
      g2lds16(A + (size_t)(m0 + row) * K + k0 + cg * 8, &As[bb][flat * 8]);
    }
    #pragma unroll
    for (int it = 0; it < BN / 64; it++) {
      int flat = it * 256 + tid;
      int row = flat >> 2;
      int cg = (flat & 3) ^ ((row >> 1) & 3);
      g2lds16(B + (size_t)(n0 + row) * K + k0 + cg * 8, &Bs[bb][flat * 8]);
    }
  };

  stage(0, 0);
  __syncthreads();
  for (int k0 = 0; k0 < K; k0 += 32) {
    const int bb = (k0 >> 5) & 1;
    if (k0 + 32 < K) stage(k0 + 32, bb ^ 1);
    bf16x8 af[TM], bf[TN];
    #pragma unroll
    for (int i = 0; i < TM; i++)
      af[i] = *(const bf16x8*)&As[bb][(wm + i * 16 + l16) * 32 + (quad ^ sw) * 8];
    #pragma unroll
    for (int j = 0; j < TN; j++)
      bf[j] = *(const bf16x8*)&Bs[bb][(wn + j * 16 + l16) * 32 + (quad ^ sw) * 8];
    #pragma unroll
    for (int i = 0; i < TM; i++)
      #pragma unroll
      for (int j = 0; j < TN; j++)
        acc[i][j] = __builtin_amdgcn_mfma_f32_16x16x32_bf16(af[i], bf[j], acc[i][j], 0, 0, 0);
    __syncthreads();  // gates buffer reuse + drains this iter's prefetch
  }

  #pragma unroll
  for (int i = 0; i < TM; i++) {
    #pragma unroll
    for (int r = 0; r < 4; r++) {
      int m = m0 + wm + i * 16 + quad * 4 + r;
      #pragma unroll
      for (int j = 0; j < TN; j++) {
        int n = n0 + wn + j * 16 + l16;
        storev(&C[(size_t)m * N + n], acc[i][j][r] + bias[n]);
      }
    }
  }
}

// =====================================================================
// V transpose -> kt-tile-major, k-chunk4-major layout:
// vt[bh][kt][c4][d][i]  (short index = (((bh*32+kt)*8 + c4)*256 + d)*4 + i)
// where element = V[key = kt*32 + c4*4 + i][d].
// =====================================================================
__global__ __launch_bounds__(256) void transpose_v(
    const unsigned short* __restrict__ proj, unsigned short* __restrict__ vt) {
  __shared__ unsigned short T[64][66];
  const int tid = threadIdx.x;
  const int s0 = blockIdx.x * 64, d0 = blockIdx.y * 64, bh = blockIdx.z;
  const int b = bh >> 3, h = bh & 7;
  #pragma unroll
  for (int it = 0; it < 2; it++) {
    int c = it * 256 + tid;
    int sr = c >> 3, d8 = (c & 7) * 8;
    int s = s0 + sr;
    const unsigned short* src = proj + (size_t)(b * SQL + h * 128 + (s >> 3)) * NKV
                                + 2 * 2048 + (s & 7) * 256 + d0 + d8;
    *(ulonglong2*)&T[sr][d8] = *(const ulonglong2*)src;
  }
  __syncthreads();
  #pragma unroll
  for (int it = 0; it < 2; it++) {
    int c = it * 256 + tid;
    int dr = c & 63, sg = c >> 6;          // sg in 0..7 (8 keys each)
    unsigned short tmp[8];
    #pragma unroll
    for (int j = 0; j < 8; j++) tmp[j] = T[sg * 8 + j][dr];
    const int d = d0 + dr;
    const int t = (s0 >> 5) + (sg >> 2);   // kt tile index
    const int c4 = (sg & 3) * 2;           // first k-chunk4 of this 8-key group
    unsigned short* base = vt + (((size_t)(bh * 32 + t) * 8 + c4) * 256 + d) * 4;
    uint2 w0, w1;
    w0.x = (unsigned)tmp[0] | ((unsigned)tmp[1] << 16);
    w0.y = (unsigned)tmp[2] | ((unsigned)tmp[3] << 16);
    w1.x = (unsigned)tmp[4] | ((unsigned)tmp[5] << 16);
    w1.y = (unsigned)tmp[6] | ((unsigned)tmp[7] << 16);
    *(uint2*)base          = w0;           // chunk c4
    *(uint2*)(base + 1024) = w1;           // chunk c4+1 (+256*4 shorts)
  }
}

// =====================================================================
// bf16 MFMA flash attention, round 10: R7 structure + REGISTER DIET.
// R3/R6/R7 pinned the law: trace VGPR_Count EXCLUDES the AGPR
// accumulators; the unified-file alloc quantum is {64,128,256} total.
// R7 = 76 arch + 64 AGPR (o[16]) = 140 > 128 -> 2 waves/SIMD -> one
// barrier-coupled 8-wave block/CU -> 66us (worse than R0's two
// independent blocks). R3 = 64+32 = 96 <= 128 -> 4/SIMD -> 27.9% occ.
// Diet: replace per-iter staging address re-derivation (the ~15-VGPR
// fat) with PERSISTENT POINTERS advanced by constants: K src += 4*NKV
// shorts/iter, V src += 8192, LDS offset ^= 16384. Target: arch <= 64,
// total <= 128 -> 4 waves/SIMD, 2 co-resident blocks (LDS 71KB x2 fits).
// Structure unchanged from R7 (validated correct): 8 waves (qs,kh),
// key-half QK (8 MFMA, no dup), private half-softmax + Ps, PV via
// 16x16x16 MFMA over full d, cross-kh O/l merge in epilogue via dead
// buffer LDS. One barrier per kt, wave-independent between barriers.
// =====================================================================
__global__ __launch_bounds__(512, 2) void attn_mfma(
    const unsigned short* __restrict__ proj,
    const unsigned short* __restrict__ vt,
    unsigned short* __restrict__ oflat) {
  // shorts: buf0 @0 (K 8192 | V 8192) | buf1 @16384 | Ps @32768 (8 x 16 x PSTR)
  __shared__ __align__(16) unsigned short lds[32768 + 8 * 16 * PSTR];
  __shared__ float lsumX[4][16];
  unsigned short* Ps = lds + 32768;

  const int tid = threadIdx.x;          // 0..511
  const int wave = tid >> 6, lane = tid & 63;
  const int quad = lane >> 4, l16 = lane & 15;
  const int qs = wave >> 1;             // q-row subtile: rows qs*16..+15
  const int kh = wave & 1;              // key half within each kt tile
  // balanced decode: slot s -> (bh = s&31, j = s>>5); round 0 heavy, 1 light
  const int slot = blockIdx.x & 255, round = blockIdx.x >> 8;
  const int bh = slot & 31;
  const int jj = slot >> 5;
  const int qt = round ? jj : 15 - jj;
  const int b = bh >> 3, h = bh & 7;
  const int q0 = qt * 64;

  // ---- persistent staging state (register diet) ----
  // K: thread covers rows r0=tid>>5 (it0) and r0+16 (it1) of each 32-row
  // K tile; chunk ch = (tid&31)^(r0&7) is kt-invariant. Advancing kt by 1
  // advances s by 32 -> (s>>3) by 4 -> src by 4*NKV shorts; it1 offset is
  // a constant 2*NKV. V: flat tile copy, += 8192/iter, it1 offset 4096.
  {
  }
  const int r0 = tid >> 5;
  const int ch0 = (tid & 31) ^ (r0 & 7);
  const unsigned short* kp = proj + (size_t)(b * SQL + h * 128 + r0) * NKV + 2048
                             + ch0 * 8;  // note: r0 = (s>>3) for kt=0,it=0 since s=r0*... 
  // careful: for kt tile row r (0..31), s = kt*32 + r; (s>>3) = 4*kt + (r>>3),
  // (s&7) = r&7. With r = r0 (it0): src = base + (4kt + (r0>>3))*NKV + (r0&7)*256 + ch0*8.
  kp = proj + (size_t)(b * SQL + h * 128 + (r0 >> 3)) * NKV + 2048
       + (r0 & 7) * 256 + ch0 * 8;
  const unsigned short* vp = vt + (size_t)bh * 262144 + tid * 8;
  unsigned soff = 0;

  auto stage = [&]() {
    unsigned short* B = lds + soff;
    g2lds16(kp,            B + tid * 8);            // K rows r0      (it0)
    g2lds16(kp + 2 * NKV,  B + 4096 + tid * 8);     // K rows r0+16   (it1)
    g2lds16(vp,            B + 8192 + tid * 8);     // V half 0
    g2lds16(vp + 4096,     B + 12288 + tid * 8);    // V half 1
    kp += 4 * NKV; vp += 8192; soff ^= 16384;
  };

  // ---- prologue: kt0 -> buf0, Q (64x256, 32KB) -> buf1 region ----
  stage();
  #pragma unroll
  for (int it = 0; it < 4; it++) {
    int c = it * 512 + tid;
    int r = c >> 5, qch = (c & 31) ^ (r & 7);
    int s = q0 + r;
    g2lds16(proj + (size_t)(b * SQL + h * 128 + (s >> 3)) * NKV + (s & 7) * 256 + qch * 8,
            lds + 16384 + c * 8);
  }
  __syncthreads();
  bf16x8 aq[8];
  const int qrow = qs * 16 + l16;
  #pragma unroll
  for (int kk = 0; kk < 8; kk++)
    aq[kk] = *(const bf16x8*)&lds[16384 + qrow * 256 + ((kk * 4 + quad) ^ (qrow & 7)) * 8];
  __syncthreads();  // all waves done reading Q before buf1 overwrite

  f32x4 o[16];
  #pragma unroll
  for (int t = 0; t < 16; t++) o[t] = {0.f, 0.f, 0.f, 0.f};
  float l_r[4] = {0.f, 0.f, 0.f, 0.f};

  const int nkt = 2 * qt + 2;
  for (int kt = 0; kt < nkt; kt++) {
    if (kt + 1 < nkt) stage();  // prefetch kt+1 into the other buffer
    const unsigned short* KsB = lds + ((kt & 1) << 14);
    const unsigned short* VtB = KsB + 8192;
    // wave's 16 keys: kt*32 + kh*16 .. +15; skip if fully masked
    const bool live = (kt * 32 + kh * 16 <= q0 + qs * 16 + 15);

    if (live) {
      // ---- S = Q K^T : 16 q-rows x my 16-key half (8 MFMA) ----
      f32x4 s0 = {0.f, 0.f, 0.f, 0.f};
      const int krow = kh * 16 + l16;
      #pragma unroll
      for (int kk = 0; kk < 8; kk++) {
        bf16x8 bk = *(const bf16x8*)&KsB[krow * 256 + ((kk * 4 + quad) ^ (l16 & 7)) * 8];
        s0 = __builtin_amdgcn_mfma_f32_16x16x32_bf16(aq[kk], bk, s0, 0, 0, 0);
      }

      // ---- half-softmax: p = exp2(s/16*log2e), lane-local l ----
      const int kg = kt * 32 + kh * 16 + l16;
      unsigned short* PsW = Ps + wave * 16 * PSTR;  // private [16][PSTR]
      #pragma unroll
      for (int r = 0; r < 4; r++) {
        int qg = q0 + qs * 16 + quad * 4 + r;
        float p0 = (kg <= qg) ? exp2f(s0[r] * 0.09016844f) : 0.f;
        l_r[r] += p0;
        PsW[(quad * 4 + r) * PSTR + l16] = f2bf(p0);
      }

      // ---- PV over my 16-key half, full d=256 ----
#if HAVE_MFMA16
      bf16x4 ap = *(const bf16x4*)&PsW[l16 * PSTR + quad * 4];
      #pragma unroll
      for (int tl = 0; tl < 16; tl++) {
        const int d = tl * 16 + l16;
        bf16x4 bv = *(const bf16x4*)&VtB[((kh * 4 + quad) * 256 + d) * 4];
        o[tl] = MFMA16(ap, bv, o[tl]);
      }
#else
      bf16x8 ap8;
      if (quad < 2) ap8 = *(const bf16x8*)&PsW[l16 * PSTR + quad * 8];
      else          ap8 = bf16x8{0, 0, 0, 0, 0, 0, 0, 0};
      const int c4a = kh * 4 + (quad & 1) * 2;
      #pragma unroll
      for (int tl = 0; tl < 16; tl++) {
        const int d = tl * 16 + l16;
        union { bf16x8 v8; bf16x4 v4[2]; } bvu;
        bvu.v4[0] = *(const bf16x4*)&VtB[(c4a * 256 + d) * 4];
        bvu.v4[1] = *(const bf16x4*)&VtB[((c4a + 1) * 256 + d) * 4];
        o[tl] = __builtin_amdgcn_mfma_f32_16x16x32_bf16(ap8, bvu.v8, o[tl], 0, 0, 0);
      }
#endif
    }
    __syncthreads();  // buffer reuse gate + drains this iter's prefetch
  }

  // ---- epilogue: wave-local l reduce, cross-kh O/l sum via dead LDS ----
  float lr[4];
  #pragma unroll
  for (int r = 0; r < 4; r++) {
    float l = l_r[r];
    #pragma unroll
    for (int off = 1; off < 16; off <<= 1) l += __shfl_xor(l, off);
    lr[r] = l;
  }
  if (kh == 1) {
    f32x4* ob = (f32x4*)lds;   // 4 qs x 16 t x 64 lanes x 16B = 64KB (buffers, dead)
    #pragma unroll
    for (int t = 0; t < 16; t++) ob[(qs * 16 + t) * 64 + lane] = o[t];
    if (l16 == 0) {
      #pragma unroll
      for (int r = 0; r < 4; r++) lsumX[qs][quad * 4 + r] = lr[r];
    }
  }
  __syncthreads();
  if (kh == 0) {
    const f32x4* ob = (const f32x4*)lds;
    #pragma unroll
    for (int t = 0; t < 16; t++) o[t] += ob[(qs * 16 + t) * 64 + lane];
    float inv[4];
    #pragma unroll
    for (int r = 0; r < 4; r++) inv[r] = 1.0f / (lr[r] + lsumX[qs][quad * 4 + r]);
    #pragma unroll
    for (int r = 0; r < 4; r++) {
      int s = q0 + qs * 16 + quad * 4 + r;
      unsigned short* dst = oflat + (size_t)(b * SQL + h * 128 + (s >> 3)) * 2048 + (s & 7) * 256;
      #pragma unroll
      for (int t = 0; t < 16; t++)
        dst[t * 16 + l16] = f2bf(o[t][r] * inv[r]);
    }
  }
}

extern "C" void kernel_launch(void* const* d_in, const int* in_sizes, int n_in,
                              void* d_out, int out_size, void* d_ws, size_t ws_size,
                              hipStream_t stream) {
  const float* x      = (const float*)d_in[0];
  const float* w_attn = (const float*)d_in[1];
  const float* b_attn = (const float*)d_in[2];
  const float* w_out  = (const float*)d_in[3];
  const float* b_out  = (const float*)d_in[4];
  float* out = (float*)d_out;

  char* p = (char*)d_ws;
  unsigned short* proj = (unsigned short*)p;  p += (size_t)MROWS * NKV * 2;
  unsigned short* obf  = (unsigned short*)p;  p += (size_t)MROWS * 2048 * 2;
  unsigned short* vtb  = (unsigned short*)p;  p += (size_t)32 * EDIM * SQL * 2;
  unsigned short* xb   = (unsigned short*)p;  p += (size_t)MROWS * EDIM * 2;
  unsigned short* wb   = (unsigned short*)p;  p += (size_t)NKV * EDIM * 2;
  unsigned short* wob  = (unsigned short*)p;

  const int n0 = MROWS * EDIM / 8;        // 131072 -> 512 blocks
  const int n1 = NKV * EDIM / 8;          // 196608 -> 768 blocks
  const int n2 = EDIM * 2048 / 8;         // 65536  -> 256 blocks
  cast3_bf16<<<(n0 + n1 + n2) / 256, 256, 0, stream>>>(x, xb, n0, w_attn, wb, n1,
                                                       w_out, wob, n2);

  gemm_mfma<128, 128, unsigned short><<<dim3(MROWS / 128, NKV / 128), 256, 0, stream>>>(
      xb, wb, b_attn, proj, MROWS, NKV, EDIM);
  transpose_v<<<dim3(SQL / 64, EDIM / 64, 32), 256, 0, stream>>>(proj, vtb);
  attn_mfma<<<512, 512, 0, stream>>>(proj, vtb, obf);
  gemm_mfma<64, 64, float><<<dim3(MROWS / 64, EDIM / 64), 256, 0, stream>>>(
      obf, wob, b_out, out, MROWS, EDIM, NHD * EDIM);
}

// Round 9
// 185.663 us; speedup vs baseline: 1.0106x; 1.0106x over previous
//
#include <hip/hip_runtime.h>

#define SQL  1024
#define EDIM 256
#define NHD  8
#define NKV  (NHD * 3 * EDIM)   // 6144
#define MROWS (4 * SQL)         // 4096

typedef short bf16x8 __attribute__((ext_vector_type(8)));
typedef short bf16x4 __attribute__((ext_vector_type(4)));
typedef float f32x4 __attribute__((ext_vector_type(4)));

// ---- 16x16x16 bf16 MFMA builtin resolution (guarded; fallback = zero-padded 16x16x32)
#if defined(__has_builtin)
#if __has_builtin(__builtin_amdgcn_mfma_f32_16x16x16bf16_1k)
#define MFMA16(a, b, c) __builtin_amdgcn_mfma_f32_16x16x16bf16_1k(a, b, c, 0, 0, 0)
#define HAVE_MFMA16 1
#elif __has_builtin(__builtin_amdgcn_mfma_f32_16x16x16_bf16)
#define MFMA16(a, b, c) __builtin_amdgcn_mfma_f32_16x16x16_bf16(a, b, c, 0, 0, 0)
#define HAVE_MFMA16 1
#else
#define HAVE_MFMA16 0
#endif
#else
#define HAVE_MFMA16 0
#endif

// Ps row stride (shorts): 20 (=40B, b64-aligned) for the 16x16x16 path;
// 24 (=48B, 16B-aligned) for the b128 fallback path.
constexpr int PSTR = HAVE_MFMA16 ? 20 : 24;

__device__ __forceinline__ unsigned short f2bf(float f) {
  unsigned u = __float_as_uint(f);
  u += 0x7fff + ((u >> 16) & 1);   // round-to-nearest-even (finite values)
  return (unsigned short)(u >> 16);
}

// async 16B global->LDS (direct-to-shared DMA; LDS dest must be
// wave-uniform base + lane*16 — all call sites use flat tid*16B forms)
__device__ __forceinline__ void g2lds16(const void* g, void* l) {
  __builtin_amdgcn_global_load_lds(
      (const __attribute__((address_space(1))) unsigned int*)g,
      (__attribute__((address_space(3))) unsigned int*)l, 16, 0, 0);
}

__device__ __forceinline__ void storev(float* p, float v) { *p = v; }
__device__ __forceinline__ void storev(unsigned short* p, float v) { *p = f2bf(v); }

// =====================================================================
// fused fp32 -> bf16 cast for all three inputs, 8 elems/thread.
// =====================================================================
__global__ __launch_bounds__(256) void cast3_bf16(
    const float* __restrict__ s0, unsigned short* __restrict__ d0, int n0,
    const float* __restrict__ s1, unsigned short* __restrict__ d1, int n1,
    const float* __restrict__ s2, unsigned short* __restrict__ d2, int n2) {
  int i = blockIdx.x * 256 + threadIdx.x;
  const float* s; unsigned short* d;
  if (i < n0) { s = s0; d = d0; }
  else if (i < n0 + n1) { i -= n0; s = s1; d = d1; }
  else { i -= n0 + n1; if (i >= n2) return; s = s2; d = d2; }
  float4 a = ((const float4*)s)[2 * i];
  float4 b = ((const float4*)s)[2 * i + 1];
  union { unsigned short u[8]; ulonglong2 v; } t;
  t.u[0] = f2bf(a.x); t.u[1] = f2bf(a.y); t.u[2] = f2bf(a.z); t.u[3] = f2bf(a.w);
  t.u[4] = f2bf(b.x); t.u[5] = f2bf(b.y); t.u[6] = f2bf(b.z); t.u[7] = f2bf(b.w);
  ((ulonglong2*)d)[i] = t.v;
}

// =====================================================================
// bf16 MFMA NT-GEMM, double-buffered global_load_lds staging.
// (round-0 proven version)
// =====================================================================
template <int BM, int BN, typename OutT>
__global__ __launch_bounds__(256) void gemm_mfma(
    const unsigned short* __restrict__ A, const unsigned short* __restrict__ B,
    const float* __restrict__ bias, OutT* __restrict__ C,
    int M, int N, int K) {
  constexpr int TM = BM / 32, TN = BN / 32;
  __shared__ __align__(16) unsigned short As[2][BM * 32];
  __shared__ __align__(16) unsigned short Bs[2][BN * 32];
  const int tid = threadIdx.x;
  const int wave = tid >> 6, lane = tid & 63;
  const int quad = lane >> 4, l16 = lane & 15;
  const int wm = (wave >> 1) * (BM / 2), wn = (wave & 1) * (BN / 2);
  const int m0 = blockIdx.x * BM, n0 = blockIdx.y * BN;
  const int sw = (l16 >> 1) & 3;

  f32x4 acc[TM][TN];
  #pragma unroll
  for (int i = 0; i < TM; i++)
    #pragma unroll
    for (int j = 0; j < TN; j++) acc[i][j] = {0.f, 0.f, 0.f, 0.f};

  auto stage = [&](int k0, int bb) {
    #pragma unroll
    for (int it = 0; it < BM / 64; it++) {
      int flat = it * 256 + tid;
      int row = flat >> 2;
      int cg = (flat & 3) ^ ((row >> 1) & 3);
      g2lds16(A + (size_t)(m0 + row) * K + k0 + cg * 8, &As[bb][flat * 8]);
    }
    #pragma unroll
    for (int it = 0; it < BN / 64; it++) {
      int flat = it * 256 + tid;
      int row = flat >> 2;
      int cg = (flat & 3) ^ ((row >> 1) & 3);
      g2lds16(B + (size_t)(n0 + row) * K + k0 + cg * 8, &Bs[bb][flat * 8]);
    }
  };

  stage(0, 0);
  __syncthreads();
  for (int k0 = 0; k0 < K; k0 += 32) {
    const int bb = (k0 >> 5) & 1;
    if (k0 + 32 < K) stage(k0 + 32, bb ^ 1);
    bf16x8 af[TM], bf[TN];
    #pragma unroll
    for (int i = 0; i < TM; i++)
      af[i] = *(const bf16x8*)&As[bb][(wm + i * 16 + l16) * 32 + (quad ^ sw) * 8];
    #pragma unroll
    for (int j = 0; j < TN; j++)
      bf[j] = *(const bf16x8*)&Bs[bb][(wn + j * 16 + l16) * 32 + (quad ^ sw) * 8];
    #pragma unroll
    for (int i = 0; i < TM; i++)
      #pragma unroll
      for (int j = 0; j < TN; j++)
        acc[i][j] = __builtin_amdgcn_mfma_f32_16x16x32_bf16(af[i], bf[j], acc[i][j], 0, 0, 0);
    __syncthreads();  // gates buffer reuse + drains this iter's prefetch
  }

  #pragma unroll
  for (int i = 0; i < TM; i++) {
    #pragma unroll
    for (int r = 0; r < 4; r++) {
      int m = m0 + wm + i * 16 + quad * 4 + r;
      #pragma unroll
      for (int j = 0; j < TN; j++) {
        int n = n0 + wn + j * 16 + l16;
        storev(&C[(size_t)m * N + n], acc[i][j][r] + bias[n]);
      }
    }
  }
}

// =====================================================================
// V transpose -> kt-tile-major, k-chunk4-major layout:
// vt[bh][kt][c4][d][i]  (short index = (((bh*32+kt)*8 + c4)*256 + d)*4 + i)
// where element = V[key = kt*32 + c4*4 + i][d].
// =====================================================================
__global__ __launch_bounds__(256) void transpose_v(
    const unsigned short* __restrict__ proj, unsigned short* __restrict__ vt) {
  __shared__ unsigned short T[64][66];
  const int tid = threadIdx.x;
  const int s0 = blockIdx.x * 64, d0 = blockIdx.y * 64, bh = blockIdx.z;
  const int b = bh >> 3, h = bh & 7;
  #pragma unroll
  for (int it = 0; it < 2; it++) {
    int c = it * 256 + tid;
    int sr = c >> 3, d8 = (c & 7) * 8;
    int s = s0 + sr;
    const unsigned short* src = proj + (size_t)(b * SQL + h * 128 + (s >> 3)) * NKV
                                + 2 * 2048 + (s & 7) * 256 + d0 + d8;
    *(ulonglong2*)&T[sr][d8] = *(const ulonglong2*)src;
  }
  __syncthreads();
  #pragma unroll
  for (int it = 0; it < 2; it++) {
    int c = it * 256 + tid;
    int dr = c & 63, sg = c >> 6;          // sg in 0..7 (8 keys each)
    unsigned short tmp[8];
    #pragma unroll
    for (int j = 0; j < 8; j++) tmp[j] = T[sg * 8 + j][dr];
    const int d = d0 + dr;
    const int t = (s0 >> 5) + (sg >> 2);   // kt tile index
    const int c4 = (sg & 3) * 2;           // first k-chunk4 of this 8-key group
    unsigned short* base = vt + (((size_t)(bh * 32 + t) * 8 + c4) * 256 + d) * 4;
    uint2 w0, w1;
    w0.x = (unsigned)tmp[0] | ((unsigned)tmp[1] << 16);
    w0.y = (unsigned)tmp[2] | ((unsigned)tmp[3] << 16);
    w1.x = (unsigned)tmp[4] | ((unsigned)tmp[5] << 16);
    w1.y = (unsigned)tmp[6] | ((unsigned)tmp[7] << 16);
    *(uint2*)base          = w0;           // chunk c4
    *(uint2*)(base + 1024) = w1;           // chunk c4+1 (+256*4 shorts)
  }
}

// =====================================================================
// bf16 MFMA flash attention, round 11: INDEPENDENT-BLOCK restructure.
// Series evidence: R0 (2 independent 4-wave blocks/CU, 8 waves/CU) =
// 47us; R8 (1 coupled 8-wave block/CU, 8 waves/CU, HALF the per-wave
// work) = 67us. Same wave count -> independence between barrier
// domains is the lever, not waves/SIMD. Register diets failed twice
// (allocator ignores source restructuring; VGPR 76 both times).
// This round: QBLK 32, 256-thread blocks (4 waves: qs{0,1} x kh{0,1}),
// grid 1024 (same heavy/light pairing). Per-wave role = R8 exactly
// (16 q-rows, private 16-key half QK = 8 MFMA, private half-softmax,
// MFMA16 PV over full d, cross-kh epilogue merge). LDS = 2x32KB dbuf
// + Ps 2.5KB ~ 69KB -> 2 independent blocks/CU at ANY reg count in
// (128,256] (LDS caps residency, so the 140-reg total is harmless).
// FETCH doubles (K/V per 32-row block) - deliberate, we're at 9% HBM.
// One barrier per kt, full wave independence between barriers.
// =====================================================================
__global__ __launch_bounds__(256, 2) void attn_mfma(
    const unsigned short* __restrict__ proj,
    const unsigned short* __restrict__ vt,
    unsigned short* __restrict__ oflat) {
  // shorts: buf0 @0 (K 8192 | V 8192) | buf1 @16384 | Ps @32768 (4 x 16 x PSTR)
  __shared__ __align__(16) unsigned short lds[32768 + 4 * 16 * PSTR];
  __shared__ float lsumX[2][16];
  unsigned short* Ps = lds + 32768;

  const int tid = threadIdx.x;          // 0..255
  const int wave = tid >> 6, lane = tid & 63;
  const int quad = lane >> 4, l16 = lane & 15;
  const int qs = wave >> 1;             // q-row subtile: rows qs*16..+15 (0..1)
  const int kh = wave & 1;              // key half within each kt tile
  // balanced decode over 1024 blocks: round 0 = qt 31..16 (heavy),
  // round 1 = qt 0..15 (light); 512 concurrent slots = exactly round 0.
  const int slot = blockIdx.x & 511, round = blockIdx.x >> 9;
  const int bh = slot & 31;
  const int jj = slot >> 5;             // 0..15
  const int qt = round ? jj : 31 - jj;  // 0..31
  const int b = bh >> 3, h = bh & 7;
  const int q0 = qt * 32;

  auto stage = [&](int kt, int bb) {
    unsigned short* B = lds + bb * 16384;
    #pragma unroll
    for (int it = 0; it < 4; it++) {   // K tile 32 x 256 (16KB), swizzled
      int c = it * 256 + tid;
      int r = c >> 5, ch = (c & 31) ^ (r & 7);
      int s = kt * 32 + r;
      g2lds16(proj + (size_t)(b * SQL + h * 128 + (s >> 3)) * NKV + 2048 + (s & 7) * 256 + ch * 8,
              B + c * 8);
    }
    const unsigned short* vsrc = vt + ((size_t)bh * 32 + kt) * 8192;
    #pragma unroll
    for (int it = 0; it < 4; it++) {   // V tile: flat 16KB copy (tile-major layout)
      int c = it * 256 + tid;
      g2lds16(vsrc + c * 8, B + 8192 + c * 8);
    }
  };

  // ---- prologue: kt0 -> buf0, Q (32x256, 16KB) -> buf1 region ----
  stage(0, 0);
  #pragma unroll
  for (int it = 0; it < 4; it++) {
    int c = it * 256 + tid;
    int r = c >> 5, qch = (c & 31) ^ (r & 7);   // r in 0..31
    int s = q0 + r;
    g2lds16(proj + (size_t)(b * SQL + h * 128 + (s >> 3)) * NKV + (s & 7) * 256 + qch * 8,
            lds + 16384 + c * 8);
  }
  __syncthreads();
  bf16x8 aq[8];
  const int qrow = qs * 16 + l16;   // 0..31
  #pragma unroll
  for (int kk = 0; kk < 8; kk++)
    aq[kk] = *(const bf16x8*)&lds[16384 + qrow * 256 + ((kk * 4 + quad) ^ (qrow & 7)) * 8];
  __syncthreads();  // all waves done reading Q before buf1 overwrite

  f32x4 o[16];
  #pragma unroll
  for (int t = 0; t < 16; t++) o[t] = {0.f, 0.f, 0.f, 0.f};
  float l_r[4] = {0.f, 0.f, 0.f, 0.f};

  const int nkt = qt + 1;
  for (int kt = 0; kt < nkt; kt++) {
    const int bb = kt & 1;
    if (kt + 1 < nkt) stage(kt + 1, bb ^ 1);  // prefetch into other buffer
    const unsigned short* KsB = lds + (bb << 14);
    const unsigned short* VtB = KsB + 8192;
    // wave's 16 keys: kt*32 + kh*16 .. +15; skip if fully masked
    const bool live = (kt * 32 + kh * 16 <= q0 + qs * 16 + 15);

    if (live) {
      // ---- S = Q K^T : 16 q-rows x my 16-key half (8 MFMA) ----
      f32x4 s0 = {0.f, 0.f, 0.f, 0.f};
      const int krow = kh * 16 + l16;
      #pragma unroll
      for (int kk = 0; kk < 8; kk++) {
        bf16x8 bk = *(const bf16x8*)&KsB[krow * 256 + ((kk * 4 + quad) ^ (l16 & 7)) * 8];
        s0 = __builtin_amdgcn_mfma_f32_16x16x32_bf16(aq[kk], bk, s0, 0, 0, 0);
      }

      // ---- half-softmax: p = exp2(s/16*log2e), lane-local l ----
      const int kg = kt * 32 + kh * 16 + l16;
      unsigned short* PsW = Ps + wave * 16 * PSTR;  // private [16][PSTR]
      #pragma unroll
      for (int r = 0; r < 4; r++) {
        int qg = q0 + qs * 16 + quad * 4 + r;
        float p0 = (kg <= qg) ? exp2f(s0[r] * 0.09016844f) : 0.f;
        l_r[r] += p0;
        PsW[(quad * 4 + r) * PSTR + l16] = f2bf(p0);
      }

      // ---- PV over my 16-key half, full d=256 ----
#if HAVE_MFMA16
      bf16x4 ap = *(const bf16x4*)&PsW[l16 * PSTR + quad * 4];
      #pragma unroll
      for (int tl = 0; tl < 16; tl++) {
        const int d = tl * 16 + l16;
        bf16x4 bv = *(const bf16x4*)&VtB[((kh * 4 + quad) * 256 + d) * 4];
        o[tl] = MFMA16(ap, bv, o[tl]);
      }
#else
      bf16x8 ap8;
      if (quad < 2) ap8 = *(const bf16x8*)&PsW[l16 * PSTR + quad * 8];
      else          ap8 = bf16x8{0, 0, 0, 0, 0, 0, 0, 0};
      const int c4a = kh * 4 + (quad & 1) * 2;
      #pragma unroll
      for (int tl = 0; tl < 16; tl++) {
        const int d = tl * 16 + l16;
        union { bf16x8 v8; bf16x4 v4[2]; } bvu;
        bvu.v4[0] = *(const bf16x4*)&VtB[(c4a * 256 + d) * 4];
        bvu.v4[1] = *(const bf16x4*)&VtB[((c4a + 1) * 256 + d) * 4];
        o[tl] = __builtin_amdgcn_mfma_f32_16x16x32_bf16(ap8, bvu.v8, o[tl], 0, 0, 0);
      }
#endif
    }
    __syncthreads();  // buffer reuse gate + drains this iter's prefetch
  }

  // ---- epilogue: wave-local l reduce, cross-kh O/l sum via dead LDS ----
  float lr[4];
  #pragma unroll
  for (int r = 0; r < 4; r++) {
    float l = l_r[r];
    #pragma unroll
    for (int off = 1; off < 16; off <<= 1) l += __shfl_xor(l, off);
    lr[r] = l;
  }
  if (kh == 1) {
    f32x4* ob = (f32x4*)lds;   // 2 qs x 16 t x 64 lanes x 16B = 32KB (buffers, dead)
    #pragma unroll
    for (int t = 0; t < 16; t++) ob[(qs * 16 + t) * 64 + lane] = o[t];
    if (l16 == 0) {
      #pragma unroll
      for (int r = 0; r < 4; r++) lsumX[qs][quad * 4 + r] = lr[r];
    }
  }
  __syncthreads();
  if (kh == 0) {
    const f32x4* ob = (const f32x4*)lds;
    #pragma unroll
    for (int t = 0; t < 16; t++) o[t] += ob[(qs * 16 + t) * 64 + lane];
    float inv[4];
    #pragma unroll
    for (int r = 0; r < 4; r++) inv[r] = 1.0f / (lr[r] + lsumX[qs][quad * 4 + r]);
    #pragma unroll
    for (int r = 0; r < 4; r++) {
      int s = q0 + qs * 16 + quad * 4 + r;
      unsigned short* dst = oflat + (size_t)(b * SQL + h * 128 + (s >> 3)) * 2048 + (s & 7) * 256;
      #pragma unroll
      for (int t = 0; t < 16; t++)
        dst[t * 16 + l16] = f2bf(o[t][r] * inv[r]);
    }
  }
}

extern "C" void kernel_launch(void* const* d_in, const int* in_sizes, int n_in,
                              void* d_out, int out_size, void* d_ws, size_t ws_size,
                              hipStream_t stream) {
  const float* x      = (const float*)d_in[0];
  const float* w_attn = (const float*)d_in[1];
  const float* b_attn = (const float*)d_in[2];
  const float* w_out  = (const float*)d_in[3];
  const float* b_out  = (const float*)d_in[4];
  float* out = (float*)d_out;

  char* p = (char*)d_ws;
  unsigned short* proj = (unsigned short*)p;  p += (size_t)MROWS * NKV * 2;
  unsigned short* obf  = (unsigned short*)p;  p += (size_t)MROWS * 2048 * 2;
  unsigned short* vtb  = (unsigned short*)p;  p += (size_t)32 * EDIM * SQL * 2;
  unsigned short* xb   = (unsigned short*)p;  p += (size_t)MROWS * EDIM * 2;
  unsigned short* wb   = (unsigned short*)p;  p += (size_t)NKV * EDIM * 2;
  unsigned short* wob  = (unsigned short*)p;

  const int n0 = MROWS * EDIM / 8;        // 131072 -> 512 blocks
  const int n1 = NKV * EDIM / 8;          // 196608 -> 768 blocks
  const int n2 = EDIM * 2048 / 8;         // 65536  -> 256 blocks
  cast3_bf16<<<(n0 + n1 + n2) / 256, 256, 0, stream>>>(x, xb, n0, w_attn, wb, n1,
                                                       w_out, wob, n2);

  gemm_mfma<128, 128, unsigned short><<<dim3(MROWS / 128, NKV / 128), 256, 0, stream>>>(
      xb, wb, b_attn, proj, MROWS, NKV, EDIM);
  transpose_v<<<dim3(SQL / 64, EDIM / 64, 32), 256, 0, stream>>>(proj, vtb);
  attn_mfma<<<1024, 256, 0, stream>>>(proj, vtb, obf);
  gemm_mfma<64, 64, float><<<dim3(MROWS / 64, EDIM / 64), 256, 0, stream>>>(
      obf, wob, b_out, out, MROWS, EDIM, NHD * EDIM);
}

// Round 10
// 168.216 us; speedup vs baseline: 1.1155x; 1.1037x over previous
//
#include <hip/hip_runtime.h>

#define SQL  1024
#define EDIM 256
#define NHD  8
#define NKV  (NHD * 3 * EDIM)   // 6144
#define MROWS (4 * SQL)         // 4096

typedef short bf16x8 __attribute__((ext_vector_type(8)));
typedef float f32x4 __attribute__((ext_vector_type(4)));

__device__ __forceinline__ unsigned short f2bf(float f) {
  unsigned u = __float_as_uint(f);
  u += 0x7fff + ((u >> 16) & 1);   // round-to-nearest-even (finite values)
  return (unsigned short)(u >> 16);
}

// async 16B global->LDS (direct-to-shared DMA; LDS dest must be
// wave-uniform base + lane*16 — all call sites use flat (it*256+tid)*16B)
__device__ __forceinline__ void g2lds16(const void* g, void* l) {
  __builtin_amdgcn_global_load_lds(
      (const __attribute__((address_space(1))) unsigned int*)g,
      (__attribute__((address_space(3))) unsigned int*)l, 16, 0, 0);
}

__device__ __forceinline__ void storev(float* p, float v) { *p = v; }
__device__ __forceinline__ void storev(unsigned short* p, float v) { *p = f2bf(v); }

// =====================================================================
// fused fp32 -> bf16 cast for all three inputs, 8 elems/thread.
// =====================================================================
__global__ __launch_bounds__(256) void cast3_bf16(
    const float* __restrict__ s0, unsigned short* __restrict__ d0, int n0,
    const float* __restrict__ s1, unsigned short* __restrict__ d1, int n1,
    const float* __restrict__ s2, unsigned short* __restrict__ d2, int n2) {
  int i = blockIdx.x * 256 + threadIdx.x;
  const float* s; unsigned short* d;
  if (i < n0) { s = s0; d = d0; }
  else if (i < n0 + n1) { i -= n0; s = s1; d = d1; }
  else { i -= n0 + n1; if (i >= n2) return; s = s2; d = d2; }
  float4 a = ((const float4*)s)[2 * i];
  float4 b = ((const float4*)s)[2 * i + 1];
  union { unsigned short u[8]; ulonglong2 v; } t;
  t.u[0] = f2bf(a.x); t.u[1] = f2bf(a.y); t.u[2] = f2bf(a.z); t.u[3] = f2bf(a.w);
  t.u[4] = f2bf(b.x); t.u[5] = f2bf(b.y); t.u[6] = f2bf(b.z); t.u[7] = f2bf(b.w);
  ((ulonglong2*)d)[i] = t.v;
}

// =====================================================================
// bf16 MFMA NT-GEMM, double-buffered global_load_lds staging.
// (round-0 proven version)
// =====================================================================
template <int BM, int BN, typename OutT>
__global__ __launch_bounds__(256) void gemm_mfma(
    const unsigned short* __restrict__ A, const unsigned short* __restrict__ B,
    const float* __restrict__ bias, OutT* __restrict__ C,
    int M, int N, int K) {
  constexpr int TM = BM / 32, TN = BN / 32;
  __shared__ __align__(16) unsigned short As[2][BM * 32];
  __shared__ __align__(16) unsigned short Bs[2][BN * 32];
  const int tid = threadIdx.x;
  const int wave = tid >> 6, lane = tid & 63;
  const int quad = lane >> 4, l16 = lane & 15;
  const int wm = (wave >> 1) * (BM / 2), wn = (wave & 1) * (BN / 2);
  const int m0 = blockIdx.x * BM, n0 = blockIdx.y * BN;
  const int sw = (l16 >> 1) & 3;

  f32x4 acc[TM][TN];
  #pragma unroll
  for (int i = 0; i < TM; i++)
    #pragma unroll
    for (int j = 0; j < TN; j++) acc[i][j] = {0.f, 0.f, 0.f, 0.f};

  auto stage = [&](int k0, int bb) {
    #pragma unroll
    for (int it = 0; it < BM / 64; it++) {
      int flat = it * 256 + tid;
      int row = flat >> 2;
      int cg = (flat & 3) ^ ((row >> 1) & 3);
      g2lds16(A + (size_t)(m0 + row) * K + k0 + cg * 8, &As[bb][flat * 8]);
    }
    #pragma unroll
    for (int it = 0; it < BN / 64; it++) {
      int flat = it * 256 + tid;
      int row = flat >> 2;
      int cg = (flat & 3) ^ ((row >> 1) & 3);
      g2lds16(B + (size_t)(n0 + row) * K + k0 + cg * 8, &Bs[bb][flat * 8]);
    }
  };

  stage(0, 0);
  __syncthreads();
  for (int k0 = 0; k0 < K; k0 += 32) {
    const int bb = (k0 >> 5) & 1;
    if (k0 + 32 < K) stage(k0 + 32, bb ^ 1);
    bf16x8 af[TM], bf[TN];
    #pragma unroll
    for (int i = 0; i < TM; i++)
      af[i] = *(const bf16x8*)&As[bb][(wm + i * 16 + l16) * 32 + (quad ^ sw) * 8];
    #pragma unroll
    for (int j = 0; j < TN; j++)
      bf[j] = *(const bf16x8*)&Bs[bb][(wn + j * 16 + l16) * 32 + (quad ^ sw) * 8];
    #pragma unroll
    for (int i = 0; i < TM; i++)
      #pragma unroll
      for (int j = 0; j < TN; j++)
        acc[i][j] = __builtin_amdgcn_mfma_f32_16x16x32_bf16(af[i], bf[j], acc[i][j], 0, 0, 0);
    __syncthreads();  // gates buffer reuse + drains this iter's prefetch
  }

  #pragma unroll
  for (int i = 0; i < TM; i++) {
    #pragma unroll
    for (int r = 0; r < 4; r++) {
      int m = m0 + wm + i * 16 + quad * 4 + r;
      #pragma unroll
      for (int j = 0; j < TN; j++) {
        int n = n0 + wn + j * 16 + l16;
        storev(&C[(size_t)m * N + n], acc[i][j][r] + bias[n]);
      }
    }
  }
}

// =====================================================================
// Split-K bf16 MFMA NT-GEMM for the skinny output projection:
// M=4096, N=256, K=2048. Plain 64x64 tiling gives only 256 blocks
// (1/CU) x 64 serial K-iters — a pure latency chain. Split K into
// NSPLIT chunks (blockIdx.z): 4x the blocks, 16 iters each. ks==0
// folds the bias into its accumulator init; all partitions atomicAdd
// into a pre-zeroed fp32 C (hipMemsetAsync upstream).
// =====================================================================
template <int BM, int BN, int KCH>
__global__ __launch_bounds__(256) void gemm_splitk(
    const unsigned short* __restrict__ A, const unsigned short* __restrict__ B,
    const float* __restrict__ bias, float* __restrict__ C,
    int M, int N, int K) {
  constexpr int TM = BM / 32, TN = BN / 32;
  __shared__ __align__(16) unsigned short As[2][BM * 32];
  __shared__ __align__(16) unsigned short Bs[2][BN * 32];
  const int tid = threadIdx.x;
  const int wave = tid >> 6, lane = tid & 63;
  const int quad = lane >> 4, l16 = lane & 15;
  const int wm = (wave >> 1) * (BM / 2), wn = (wave & 1) * (BN / 2);
  const int m0 = blockIdx.x * BM, n0 = blockIdx.y * BN;
  const int kbase = blockIdx.z * KCH;
  const int sw = (l16 >> 1) & 3;

  f32x4 acc[TM][TN];
  #pragma unroll
  for (int j = 0; j < TN; j++) {
    const float bb = (blockIdx.z == 0) ? bias[n0 + wn + j * 16 + l16] : 0.f;
    #pragma unroll
    for (int i = 0; i < TM; i++) acc[i][j] = {bb, bb, bb, bb};
  }

  auto stage = [&](int k0, int bb) {
    #pragma unroll
    for (int it = 0; it < BM / 64; it++) {
      int flat = it * 256 + tid;
      int row = flat >> 2;
      int cg = (flat & 3) ^ ((row >> 1) & 3);
      g2lds16(A + (size_t)(m0 + row) * K + k0 + cg * 8, &As[bb][flat * 8]);
    }
    #pragma unroll
    for (int it = 0; it < BN / 64; it++) {
      int flat = it * 256 + tid;
      int row = flat >> 2;
      int cg = (flat & 3) ^ ((row >> 1) & 3);
      g2lds16(B + (size_t)(n0 + row) * K + k0 + cg * 8, &Bs[bb][flat * 8]);
    }
  };

  stage(kbase, 0);
  __syncthreads();
  for (int kk = 0; kk < KCH; kk += 32) {
    const int bb = (kk >> 5) & 1;
    if (kk + 32 < KCH) stage(kbase + kk + 32, bb ^ 1);
    bf16x8 af[TM], bf[TN];
    #pragma unroll
    for (int i = 0; i < TM; i++)
      af[i] = *(const bf16x8*)&As[bb][(wm + i * 16 + l16) * 32 + (quad ^ sw) * 8];
    #pragma unroll
    for (int j = 0; j < TN; j++)
      bf[j] = *(const bf16x8*)&Bs[bb][(wn + j * 16 + l16) * 32 + (quad ^ sw) * 8];
    #pragma unroll
    for (int i = 0; i < TM; i++)
      #pragma unroll
      for (int j = 0; j < TN; j++)
        acc[i][j] = __builtin_amdgcn_mfma_f32_16x16x32_bf16(af[i], bf[j], acc[i][j], 0, 0, 0);
    __syncthreads();
  }

  #pragma unroll
  for (int i = 0; i < TM; i++) {
    #pragma unroll
    for (int r = 0; r < 4; r++) {
      int m = m0 + wm + i * 16 + quad * 4 + r;
      #pragma unroll
      for (int j = 0; j < TN; j++) {
        int n = n0 + wn + j * 16 + l16;
        atomicAdd(&C[(size_t)m * N + n], acc[i][j][r]);
      }
    }
  }
}

// =====================================================================
// One-shot V transpose: raw-view V -> Vt[bh][d][s] bf16. (R0 version)
// =====================================================================
__global__ __launch_bounds__(256) void transpose_v(
    const unsigned short* __restrict__ proj, unsigned short* __restrict__ vt) {
  __shared__ unsigned short T[64][66];
  const int tid = threadIdx.x;
  const int s0 = blockIdx.x * 64, d0 = blockIdx.y * 64, bh = blockIdx.z;
  const int b = bh >> 3, h = bh & 7;
  #pragma unroll
  for (int it = 0; it < 2; it++) {
    int c = it * 256 + tid;
    int sr = c >> 3, k8 = (c & 7) * 8;
    int s = s0 + sr;
    const unsigned short* src = proj + (size_t)(b * SQL + h * 128 + (s >> 3)) * NKV
                                + 2 * 2048 + (s & 7) * 256 + d0 + k8;
    *(ulonglong2*)&T[sr][k8] = *(const ulonglong2*)src;
  }
  __syncthreads();
  #pragma unroll
  for (int it = 0; it < 2; it++) {
    int c = it * 256 + tid;
    int dr = c >> 3, s8 = (c & 7) * 8;
    unsigned short tmp[8];
    #pragma unroll
    for (int j = 0; j < 8; j++) tmp[j] = T[s8 + j][dr];
    unsigned short* dst = vt + ((size_t)bh * EDIM + d0 + dr) * SQL + s0 + s8;
    *(ulonglong2*)dst = *(ulonglong2*)tmp;
  }
}

// =====================================================================
// bf16 MFMA flash attention — EXACT R0 version (47.2us, proven).
// Nine rounds of restructuring (wave role-split, parity split, key-half
// split, 8-wave blocks, register diets) all measured 53-85us: the
// kernel has a ~1200-1600 cyc/iter fixed cost (staging + barrier
// drain) and R0's few-fat-iterations shape amortizes it best.
// =====================================================================
__global__ __launch_bounds__(256) void attn_mfma(
    const unsigned short* __restrict__ proj,
    const unsigned short* __restrict__ vt,
    unsigned short* __restrict__ oflat) {
  // shorts: Ks0 @0 (8192) | Vts0 @8192 (8192) | Ks1 @16384 | Vts1 @24576 | Ps @32768 (2560)
  __shared__ __align__(16) unsigned short lds[35328];
  unsigned short* Ps = lds + 32768;  // [64][40] padded, VGPR-written

  const int tid = threadIdx.x;
  const int wave = tid >> 6, lane = tid & 63;
  const int quad = lane >> 4, l16 = lane & 15;
  // balanced decode: slot s -> (bh = s&31, j = s>>5); round 0 heavy, 1 light
  const int slot = blockIdx.x & 255, round = blockIdx.x >> 8;
  const int bh = slot & 31;
  const int j = slot >> 5;
  const int qt = round ? j : 15 - j;
  const int b = bh >> 3, h = bh & 7;
  const int q0 = qt * 64;

  // ---- stage Q (64 x 256) through buf0 region, swizzled ----
  #pragma unroll
  for (int it = 0; it < 8; it++) {
    int c = it * 256 + tid;
    int r = c >> 5, ch = (c & 31) ^ (r & 7);
    int s = q0 + r;
    g2lds16(proj + (size_t)(b * SQL + h * 128 + (s >> 3)) * NKV + (s & 7) * 256 + ch * 8,
            lds + c * 8);
  }
  __syncthreads();
  bf16x8 aq[8];
  const int qrow = wave * 16 + l16;
  #pragma unroll
  for (int kk = 0; kk < 8; kk++)
    aq[kk] = *(const bf16x8*)&lds[qrow * 256 + ((kk * 4 + quad) ^ (qrow & 7)) * 8];
  __syncthreads();  // all waves done reading Q before buf0 overwrite

  f32x4 o[16];
  #pragma unroll
  for (int t = 0; t < 16; t++) o[t] = {0.f, 0.f, 0.f, 0.f};
  float l_r[4] = {0.f, 0.f, 0.f, 0.f};

  auto stage = [&](int kt, int bb) {
    unsigned short* KsB = lds + bb * 16384;
    unsigned short* VtB = KsB + 8192;
    #pragma unroll
    for (int it = 0; it < 4; it++) {   // K tile 32 x 256
      int c = it * 256 + tid;
      int r = c >> 5, ch = (c & 31) ^ (r & 7);
      int s = kt * 32 + r;
      g2lds16(proj + (size_t)(b * SQL + h * 128 + (s >> 3)) * NKV + 2048 + (s & 7) * 256 + ch * 8,
              KsB + c * 8);
    }
    #pragma unroll
    for (int it = 0; it < 4; it++) {   // Vt tile 256 x 32
      int c = it * 256 + tid;
      int d = c >> 2, ch = (c & 3) ^ (d & 3);
      g2lds16(vt + ((size_t)bh * EDIM + d) * SQL + kt * 32 + ch * 8, VtB + c * 8);
    }
  };

  const int nkt = 2 * qt + 2;
  stage(0, 0);
  __syncthreads();  // drain kt=0 (exposed once)

  for (int kt = 0; kt < nkt; kt++) {
    const int bb = kt & 1;
    if (kt + 1 < nkt) stage(kt + 1, bb ^ 1);  // prefetch into other buffer
    const unsigned short* KsB = lds + bb * 16384;
    const unsigned short* VtB = KsB + 8192;

    // ---- S = Q K^T (two 16-col tiles) ----
    f32x4 s0 = {0.f, 0.f, 0.f, 0.f}, s1 = {0.f, 0.f, 0.f, 0.f};
    #pragma unroll
    for (int kk = 0; kk < 8; kk++) {
      int ch = (kk * 4 + quad) ^ (l16 & 7);
      bf16x8 b0 = *(const bf16x8*)&KsB[l16 * 256 + ch * 8];
      bf16x8 b1 = *(const bf16x8*)&KsB[(16 + l16) * 256 + ch * 8];
      s0 = __builtin_amdgcn_mfma_f32_16x16x32_bf16(aq[kk], b0, s0, 0, 0, 0);
      s1 = __builtin_amdgcn_mfma_f32_16x16x32_bf16(aq[kk], b1, s1, 0, 0, 0);
    }

    // ---- shift-free softmax: p = exp(s/16), lane-local l partials ----
    const int kg0 = kt * 32 + l16, kg1 = kg0 + 16;
    #pragma unroll
    for (int r = 0; r < 4; r++) {
      int qg = q0 + wave * 16 + quad * 4 + r;
      float p0 = (kg0 <= qg) ? __expf(s0[r] * 0.0625f) : 0.f;
      float p1 = (kg1 <= qg) ? __expf(s1[r] * 0.0625f) : 0.f;
      l_r[r] += p0 + p1;
      Ps[(wave * 16 + quad * 4 + r) * 40 + l16]      = f2bf(p0);
      Ps[(wave * 16 + quad * 4 + r) * 40 + 16 + l16] = f2bf(p1);
    }

    // ---- PV: P C->A layout via same-wave LDS round-trip ----
    bf16x8 ap = *(const bf16x8*)&Ps[(wave * 16 + l16) * 40 + quad * 8];
    #pragma unroll
    for (int t = 0; t < 16; t++) {
      bf16x8 bv = *(const bf16x8*)&VtB[(t * 16 + l16) * 32 + (quad ^ (l16 & 3)) * 8];
      o[t] = __builtin_amdgcn_mfma_f32_16x16x32_bf16(ap, bv, o[t], 0, 0, 0);
    }
    __syncthreads();  // buffer reuse gate + drains this iter's prefetch
  }

  // ---- epilogue: reduce l across the 16-lane group, O /= l, scatter ----
  #pragma unroll
  for (int r = 0; r < 4; r++) {
    float l = l_r[r];
    #pragma unroll
    for (int off = 1; off < 16; off <<= 1) l += __shfl_xor(l, off);
    float inv = 1.0f / l;
    int s = q0 + wave * 16 + quad * 4 + r;
    unsigned short* dst = oflat + (size_t)(b * SQL + h * 128 + (s >> 3)) * 2048 + (s & 7) * 256;
    #pragma unroll
    for (int t = 0; t < 16; t++)
      dst[t * 16 + l16] = f2bf(o[t][r] * inv);
  }
}

extern "C" void kernel_launch(void* const* d_in, const int* in_sizes, int n_in,
                              void* d_out, int out_size, void* d_ws, size_t ws_size,
                              hipStream_t stream) {
  const float* x      = (const float*)d_in[0];
  const float* w_attn = (const float*)d_in[1];
  const float* b_attn = (const float*)d_in[2];
  const float* w_out  = (const float*)d_in[3];
  const float* b_out  = (const float*)d_in[4];
  float* out = (float*)d_out;

  char* p = (char*)d_ws;
  unsigned short* proj = (unsigned short*)p;  p += (size_t)MROWS * NKV * 2;
  unsigned short* obf  = (unsigned short*)p;  p += (size_t)MROWS * 2048 * 2;
  unsigned short* vtb  = (unsigned short*)p;  p += (size_t)32 * EDIM * SQL * 2;
  unsigned short* xb   = (unsigned short*)p;  p += (size_t)MROWS * EDIM * 2;
  unsigned short* wb   = (unsigned short*)p;  p += (size_t)NKV * EDIM * 2;
  unsigned short* wob  = (unsigned short*)p;

  const int n0 = MROWS * EDIM / 8;        // 131072 -> 512 blocks
  const int n1 = NKV * EDIM / 8;          // 196608 -> 768 blocks
  const int n2 = EDIM * 2048 / 8;         // 65536  -> 256 blocks
  cast3_bf16<<<(n0 + n1 + n2) / 256, 256, 0, stream>>>(x, xb, n0, w_attn, wb, n1,
                                                       w_out, wob, n2);

  // zero the fp32 output for the split-K atomic accumulation
  hipMemsetAsync(out, 0, (size_t)MROWS * EDIM * sizeof(float), stream);

  gemm_mfma<128, 128, unsigned short><<<dim3(MROWS / 128, NKV / 128), 256, 0, stream>>>(
      xb, wb, b_attn, proj, MROWS, NKV, EDIM);
  transpose_v<<<dim3(SQL / 64, EDIM / 64, 32), 256, 0, stream>>>(proj, vtb);
  attn_mfma<<<512, 256, 0, stream>>>(proj, vtb, obf);
  gemm_splitk<64, 64, 512><<<dim3(MROWS / 64, EDIM / 64, 4), 256, 0, stream>>>(
      obf, wob, b_out, out, MROWS, EDIM, NHD * EDIM);
}